// Round 9
// baseline (1520.991 us; speedup 1.0000x reference)
//
#include <hip/hip_runtime.h>

#define B_   32
#define T_   300
#define C1_  2312
#define O1_  512
#define O2_  512
#define O3_  10
#define M_   (B_*T_)   // 9600

// ---------------- weight prep (all f64) ----------------

__global__ void calc_f(const float* __restrict__ v, const float* __restrict__ g,
                       double* __restrict__ f, int O, int C) {
    int o = blockIdx.x;
    const float* row = v + (size_t)o * C;
    double s = 0.0;
    for (int c = threadIdx.x; c < C; c += blockDim.x) {
        double x = (double)row[c];
        s += x * x;
    }
    for (int off = 32; off; off >>= 1) s += __shfl_down(s, off);
    __shared__ double wsum[4];
    int lane = threadIdx.x & 63, wv = threadIdx.x >> 6;
    if (lane == 0) wsum[wv] = s;
    __syncthreads();
    if (threadIdx.x == 0) {
        double tot = 0.0;
        for (int i = 0; i < (int)(blockDim.x >> 6); ++i) tot += wsum[i];
        f[o] = (double)g[o] / sqrt(tot);
    }
}

// wt[c*ldo + o] = v[o*C + c] * f[o]   (double)
__global__ void transpose_scale(const float* __restrict__ v, const double* __restrict__ f,
                                double* __restrict__ wt, int O, int C, int ldo) {
    __shared__ double tile[32][33];
    int c0 = blockIdx.x * 32, o0 = blockIdx.y * 32;
    int tx = threadIdx.x, ty = threadIdx.y;
    for (int k = 0; k < 4; ++k) {
        int o = o0 + ty + k * 8, c = c0 + tx;
        double val = 0.0;
        if (o < O && c < C) val = (double)v[(size_t)o * C + c] * f[o];
        tile[ty + k * 8][tx] = val;
    }
    __syncthreads();
    for (int k = 0; k < 4; ++k) {
        int c = c0 + ty + k * 8, o = o0 + tx;
        if (c < C && o < O) wt[(size_t)c * ldo + o] = tile[tx][ty + k * 8];
    }
}

// ---------------- GEMM layer 1 (f64, bitmask skip, LDS double-buffer) ----------------
// X: spike [B, C1, T] f32 (0/1) ; Wt: [C1, O1] f64 ; Z: [B, T, O1] f64
// 256 thr = 4 waves. Tile 128o x 32t, KC=16. Wave w owns t-octet w*8..+7
// (wave-uniform skips). Lane covers o = o0 + 2*lane + i (i<2): wf = one
// ds_read_b128 (2-way alias = free); C-store = coalesced double2.
// One barrier per K-tile via Ws[2] ping-pong.
__global__ __launch_bounds__(256) void gemm1(const float* __restrict__ X,
                                             const double* __restrict__ Wt,
                                             double* __restrict__ Z) {
    __shared__ double Ws[2][16][128];   // 2 x 16 KB
    __shared__ uint4  Xm4[2][4];        // 2 x 16 u32 t-masks (one per k)
    int b  = blockIdx.z;
    int o0 = blockIdx.y * 128;
    int t0 = blockIdx.x * 32;
    int tid = threadIdx.x;
    int lane = tid & 63, w8 = (tid >> 6) * 8;
    double2 acc[8];
#pragma unroll
    for (int tj = 0; tj < 8; ++tj) { acc[tj].x = 0.0; acc[tj].y = 0.0; }
    const float* Xb = X + (size_t)b * C1_ * T_;

    double2 wreg[4];
    float4 xr0, xr1;
    int kq = tid >> 2, gq = tid & 3;    // mask staging coords (tid<64)

    auto load_tile = [&](int c0) {
#pragma unroll
        for (int h = 0; h < 4; ++h) {   // 16k x 128o = 1024 double2 / 256 thr
            int idx = h * 256 + tid;
            int i = idx >> 6, od = (idx & 63) * 2;
            int c = c0 + i;
            double2 val; val.x = 0.0; val.y = 0.0;
            if (c < C1_) val = *(const double2*)(Wt + (size_t)c * O1_ + o0 + od);
            wreg[h] = val;
        }
        if (tid < 64) {
            int c = c0 + kq, t = t0 + gq * 8;
            xr0 = make_float4(0.f, 0.f, 0.f, 0.f);
            xr1 = make_float4(0.f, 0.f, 0.f, 0.f);
            if (c < C1_) {
                if (t < T_)     xr0 = *(const float4*)(Xb + (size_t)c * T_ + t);
                if (t + 4 < T_) xr1 = *(const float4*)(Xb + (size_t)c * T_ + t + 4);
            }
        }
    };
    auto store_tile = [&](int buf) {
#pragma unroll
        for (int h = 0; h < 4; ++h) {
            int idx = h * 256 + tid;
            int i = idx >> 6, od = (idx & 63) * 2;
            *(double2*)(&Ws[buf][i][od]) = wreg[h];
        }
        if (tid < 64) {
            unsigned int byte = 0;
            byte |= (xr0.x != 0.f) ? 1u   : 0u;
            byte |= (xr0.y != 0.f) ? 2u   : 0u;
            byte |= (xr0.z != 0.f) ? 4u   : 0u;
            byte |= (xr0.w != 0.f) ? 8u   : 0u;
            byte |= (xr1.x != 0.f) ? 16u  : 0u;
            byte |= (xr1.y != 0.f) ? 32u  : 0u;
            byte |= (xr1.z != 0.f) ? 64u  : 0u;
            byte |= (xr1.w != 0.f) ? 128u : 0u;
            ((unsigned char*)&Xm4[buf][0])[kq * 4 + gq] = (unsigned char)byte;
        }
    };

    load_tile(0);
    store_tile(0);
    __syncthreads();
    const int NT = (C1_ + 15) / 16;   // 145
    for (int tile = 0; tile < NT; ++tile) {
        int cur = tile & 1;
        if (tile + 1 < NT) load_tile((tile + 1) * 16);   // global -> regs (overlaps)
#pragma unroll
        for (int g = 0; g < 4; ++g) {
            uint4 q = Xm4[cur][g];
            unsigned int mks[4] = {q.x, q.y, q.z, q.w};
#pragma unroll
            for (int kk = 0; kk < 4; ++kk) {
                int k = g * 4 + kk;
                unsigned int oct = (mks[kk] >> w8) & 0xffu;
                if (oct) {   // wave-uniform execz skip
                    double2 wf = *(const double2*)(&Ws[cur][k][lane * 2]);
#pragma unroll
                    for (int tj = 0; tj < 8; ++tj) {
                        if (oct & (1u << tj)) {
                            acc[tj].x += wf.x;
                            acc[tj].y += wf.y;
                        }
                    }
                }
            }
        }
        if (tile + 1 < NT) store_tile(cur ^ 1);          // regs -> other buffer
        __syncthreads();
    }
#pragma unroll
    for (int tj = 0; tj < 8; ++tj) {
        int t = t0 + w8 + tj;
        if (t < T_)
            *(double2*)(Z + ((size_t)b * T_ + t) * O1_ + o0 + lane * 2) = acc[tj];
    }
}

// ---------------- GEMM layer 2 (f64, same structure, ballot masks) ----------------
// A: s [M, 512] f32 (0/1) ; Wt: [512, 512] f64 ; Z: [M, 512] f64
// Tile 128o x 32m, KC=16, 32 tiles, one barrier per tile.
__global__ __launch_bounds__(256) void gemm2(const float* __restrict__ A,
                                             const double* __restrict__ Wt,
                                             double* __restrict__ Z) {
    __shared__ double Ws[2][16][128];
    __shared__ uint4  Xm4[2][4];
    int m0 = blockIdx.x * 32;
    int o0 = blockIdx.y * 128;
    int tid = threadIdx.x;
    int lane = tid & 63, w8 = (tid >> 6) * 8;
    double2 acc[8];
#pragma unroll
    for (int tj = 0; tj < 8; ++tj) { acc[tj].x = 0.0; acc[tj].y = 0.0; }

    double2 wreg[4];
    float2 xr;
    int mo = tid & 31, kh = tid >> 5;

    auto load_tile = [&](int c0) {
#pragma unroll
        for (int h = 0; h < 4; ++h) {
            int idx = h * 256 + tid;
            int i = idx >> 6, od = (idx & 63) * 2;
            wreg[h] = *(const double2*)(Wt + (size_t)(c0 + i) * 512 + o0 + od);
        }
        xr = *(const float2*)(A + (size_t)(m0 + mo) * 512 + c0 + kh * 2);
    };
    auto store_tile = [&](int buf) {
#pragma unroll
        for (int h = 0; h < 4; ++h) {
            int idx = h * 256 + tid;
            int i = idx >> 6, od = (idx & 63) * 2;
            *(double2*)(&Ws[buf][i][od]) = wreg[h];
        }
        // wave w covers k = 4w + {0,1,2,3} via two ballots
        unsigned long long b0 = __ballot(xr.x != 0.f);
        unsigned long long b1 = __ballot(xr.y != 0.f);
        int w = tid >> 6;
        unsigned int* Xm = (unsigned int*)&Xm4[buf][0];
        if (lane == 0)  { Xm[4 * w]     = (unsigned int)b0;
                          Xm[4 * w + 1] = (unsigned int)b1; }
        if (lane == 32) { Xm[4 * w + 2] = (unsigned int)(b0 >> 32);
                          Xm[4 * w + 3] = (unsigned int)(b1 >> 32); }
    };

    load_tile(0);
    store_tile(0);
    __syncthreads();
    for (int tile = 0; tile < 32; ++tile) {
        int cur = tile & 1;
        if (tile + 1 < 32) load_tile((tile + 1) * 16);
#pragma unroll
        for (int g = 0; g < 4; ++g) {
            uint4 q = Xm4[cur][g];
            unsigned int mks[4] = {q.x, q.y, q.z, q.w};
#pragma unroll
            for (int kk = 0; kk < 4; ++kk) {
                int k = g * 4 + kk;
                unsigned int oct = (mks[kk] >> w8) & 0xffu;
                if (oct) {
                    double2 wf = *(const double2*)(&Ws[cur][k][lane * 2]);
#pragma unroll
                    for (int tj = 0; tj < 8; ++tj) {
                        if (oct & (1u << tj)) {
                            acc[tj].x += wf.x;
                            acc[tj].y += wf.y;
                        }
                    }
                }
            }
        }
        if (tile + 1 < 32) store_tile(cur ^ 1);
        __syncthreads();
    }
#pragma unroll
    for (int tj = 0; tj < 8; ++tj)
        *(double2*)(Z + (size_t)(m0 + w8 + tj) * 512 + o0 + lane * 2) = acc[tj];
}

// ---------------- GEMM layer 3 (f64 acc) ----------------
__global__ __launch_bounds__(256) void gemm3(const float* __restrict__ A,
                                             const double* __restrict__ Wt,
                                             double* __restrict__ Z) {
    __shared__ double w[512 * 16];
    for (int e = threadIdx.x; e < 4096; e += 256)
        ((double2*)w)[e] = ((const double2*)Wt)[e];
    __syncthreads();
    int m = blockIdx.x * 256 + threadIdx.x;
    if (m >= M_) return;
    double acc[O3_];
#pragma unroll
    for (int o = 0; o < O3_; ++o) acc[o] = 0.0;
    const float4* Ar = (const float4*)(A + (size_t)m * 512);
    for (int cq = 0; cq < 128; ++cq) {
        float4 a = Ar[cq];
        float av[4] = {a.x, a.y, a.z, a.w};
#pragma unroll
        for (int u = 0; u < 4; ++u)
#pragma unroll
            for (int o = 0; o < O3_; ++o) acc[o] += (double)av[u] * w[(cq * 4 + u) * 16 + o];
    }
    double* dst = Z + (size_t)m * 16;
#pragma unroll
    for (int o = 0; o < O3_; ++o) dst[o] = acc[o];
}

// ---------------- LIF scan + delay, layers 1/2 (O=512, f64 state) ----------------
__global__ void scan12(const double* __restrict__ Zin,  // [B, T, 512] f64
                       const int* __restrict__ delay,   // [512]
                       float* __restrict__ Sout,        // [B, T, 512] f32 spikes
                       float* __restrict__ sumOut) {
    int blk = blockIdx.x;
    int o = (blk & 7) * 64 + threadIdx.x;
    int b = blk >> 3;
    const double* z = Zin + (size_t)b * T_ * O1_ + o;
    float* s = Sout + (size_t)b * T_ * O1_ + o;
    int d = delay[o];
    for (int t = 0; t < d; ++t) s[(size_t)t * O1_] = 0.f;
    double cur = 0.0, vol = 0.0;
    float cnt = 0.f;
    for (int t4 = 0; t4 < T_; t4 += 4) {
        double zb[4];
#pragma unroll
        for (int u = 0; u < 4; ++u) zb[u] = z[(size_t)(t4 + u) * O1_];
#pragma unroll
        for (int u = 0; u < 4; ++u) {
            int t = t4 + u;
            cur = cur * 0.75 + zb[u];
            vol = vol * 0.97 + cur;
            float sp = (vol >= 1.25) ? 1.f : 0.f;
            if (sp > 0.f) vol = 0.0;
            int tw = t + d;
            if (tw < T_) { s[(size_t)tw * O1_] = sp; cnt += sp; }
        }
    }
    for (int off = 32; off; off >>= 1) cnt += __shfl_down(cnt, off);
    if (threadIdx.x == 0) atomicAdd(sumOut, cnt);
}

// ---------------- LIF scan + delay, layer 3 (O=10, f64 state) ----------------
__global__ void scan3(const double* __restrict__ Z3,  // [M, 16] f64
                      const int* __restrict__ d3,     // [10]
                      float* __restrict__ out,        // d_out: [B, 10, 300] f32
                      float* __restrict__ sumOut) {
    __shared__ double zt[T_ * 16];
    int b = blockIdx.x;
    const double2* src = (const double2*)(Z3 + (size_t)b * T_ * 16);
    for (int e = threadIdx.x; e < T_ * 8; e += 64)
        ((double2*)zt)[e] = src[e];
    __syncthreads();
    int o = threadIdx.x;
    if (o < O3_) {
        int d = d3[o];
        float* dst = out + (size_t)b * O3_ * T_ + (size_t)o * T_;
        for (int t = 0; t < d; ++t) dst[t] = 0.f;
        double cur = 0.0, vol = 0.0;
        float cnt = 0.f;
        for (int t = 0; t < T_; ++t) {
            cur = cur * 0.75 + zt[t * 16 + o];
            vol = vol * 0.97 + cur;
            float sp = (vol >= 1.25) ? 1.f : 0.f;
            if (sp > 0.f) vol = 0.0;
            int tw = t + d;
            if (tw < T_) { dst[tw] = sp; cnt += sp; }
        }
        atomicAdd(sumOut, cnt);
    }
}

__global__ void finalize(const float* __restrict__ sums, float* __restrict__ out) {
    if (threadIdx.x == 0) {
        out[0] = (float)((double)sums[0] / (double)(B_ * O1_ * T_));
        out[1] = (float)((double)sums[1] / (double)(B_ * O2_ * T_));
        out[2] = (float)((double)sums[2] / (double)(B_ * O3_ * T_));
    }
}

extern "C" void kernel_launch(void* const* d_in, const int* in_sizes, int n_in,
                              void* d_out, int out_size, void* d_ws, size_t ws_size,
                              hipStream_t stream) {
    const float* spike = (const float*)d_in[0];
    const float* v1 = (const float*)d_in[1];
    const float* g1 = (const float*)d_in[2];
    const float* v2 = (const float*)d_in[3];
    const float* g2 = (const float*)d_in[4];
    const float* v3 = (const float*)d_in[5];
    const float* g3 = (const float*)d_in[6];
    const int* d1 = (const int*)d_in[7];
    const int* d2 = (const int*)d_in[8];
    const int* d3 = (const int*)d_in[9];
    float* out = (float*)d_out;

    // Workspace (same layout as R3-R8 pass): ~72 MB total.
    double* dw = (double*)d_ws;
    size_t off = 0;
    double* f1  = dw + off; off += 512;
    double* f2  = dw + off; off += 512;
    double* f3  = dw + off; off += 16;
    double* Wt1 = dw + off; off += (size_t)C1_ * O1_;
    double* Wt2 = dw + off; off += 512 * 512;
    double* Wt3 = dw + off; off += 512 * 16;
    double* zA  = dw + off; off += (size_t)M_ * 512;
    double* z3b = dw + off; off += (size_t)M_ * 16;
    float* fw = (float*)(dw + off);
    float* sB   = fw;                        // f32 spikes, M*512
    float* sums = fw + (size_t)M_ * 512;     // 4 floats
    (void)ws_size; (void)out_size; (void)in_sizes; (void)n_in;

    hipMemsetAsync(sums, 0, 4 * sizeof(float), stream);

    calc_f<<<512, 256, 0, stream>>>(v1, g1, f1, O1_, C1_);
    calc_f<<<512, 256, 0, stream>>>(v2, g2, f2, O2_, O1_);
    calc_f<<<O3_, 256, 0, stream>>>(v3, g3, f3, O3_, O2_);

    transpose_scale<<<dim3((C1_ + 31) / 32, 16), dim3(32, 8), 0, stream>>>(v1, f1, Wt1, O1_, C1_, O1_);
    transpose_scale<<<dim3(16, 16), dim3(32, 8), 0, stream>>>(v2, f2, Wt2, O2_, O1_, O2_);
    transpose_scale<<<dim3(16, 1), dim3(32, 8), 0, stream>>>(v3, f3, Wt3, O3_, O2_, 16);

    // gemm1: 10 t-chunks x 4 o-slices (128) x 32 b = 1280 blocks (~4-5/CU)
    gemm1<<<dim3(10, 4, B_), 256, 0, stream>>>(spike, Wt1, zA);       // zA = z1 (f64)
    scan12<<<256, 64, 0, stream>>>(zA, d1, sB, sums + 0);             // sB = s1 (f32)
    gemm2<<<dim3(M_ / 32, 4), 256, 0, stream>>>(sB, Wt2, zA);         // zA = z2
    scan12<<<256, 64, 0, stream>>>(zA, d2, sB, sums + 1);             // sB = s2
    gemm3<<<(M_ + 255) / 256, 256, 0, stream>>>(sB, Wt3, z3b);        // z3b = z3
    scan3<<<B_, 64, 0, stream>>>(z3b, d3, out, sums + 2);
    finalize<<<1, 64, 0, stream>>>(sums, out + (size_t)B_ * O3_ * T_);
}

// Round 10
// 1015.156 us; speedup vs baseline: 1.4983x; 1.4983x over previous
//
#include <hip/hip_runtime.h>

#define B_   32
#define T_   300
#define C1_  2312
#define O1_  512
#define O2_  512
#define O3_  10
#define M_   (B_*T_)   // 9600
#define KSPLIT_ 1152   // 72 tiles of 16; half1 = 73 tiles (tail-guarded)

// ---------------- weight prep (all f64) ----------------

__global__ void calc_f(const float* __restrict__ v, const float* __restrict__ g,
                       double* __restrict__ f, int O, int C) {
    int o = blockIdx.x;
    const float* row = v + (size_t)o * C;
    double s = 0.0;
    for (int c = threadIdx.x; c < C; c += blockDim.x) {
        double x = (double)row[c];
        s += x * x;
    }
    for (int off = 32; off; off >>= 1) s += __shfl_down(s, off);
    __shared__ double wsum[4];
    int lane = threadIdx.x & 63, wv = threadIdx.x >> 6;
    if (lane == 0) wsum[wv] = s;
    __syncthreads();
    if (threadIdx.x == 0) {
        double tot = 0.0;
        for (int i = 0; i < (int)(blockDim.x >> 6); ++i) tot += wsum[i];
        f[o] = (double)g[o] / sqrt(tot);
    }
}

// wt[c*ldo + o] = v[o*C + c] * f[o]   (double)
__global__ void transpose_scale(const float* __restrict__ v, const double* __restrict__ f,
                                double* __restrict__ wt, int O, int C, int ldo) {
    __shared__ double tile[32][33];
    int c0 = blockIdx.x * 32, o0 = blockIdx.y * 32;
    int tx = threadIdx.x, ty = threadIdx.y;
    for (int k = 0; k < 4; ++k) {
        int o = o0 + ty + k * 8, c = c0 + tx;
        double val = 0.0;
        if (o < O && c < C) val = (double)v[(size_t)o * C + c] * f[o];
        tile[ty + k * 8][tx] = val;
    }
    __syncthreads();
    for (int k = 0; k < 4; ++k) {
        int c = c0 + ty + k * 8, o = o0 + tx;
        if (c < C && o < O) wt[(size_t)c * ldo + o] = tile[tx][ty + k * 8];
    }
}

// ---------------- GEMM layer 1 (f64, R8 structure + K-split x2) ----------------
// X: spike [B, C1, T] f32 (0/1) ; Wt: [C1, O1] f64 ; Z: [B, T, O1] f64 (ZEROED)
// 256 thr = 4 waves. Tile 256o x 32t, KC=16. blockIdx.z = b*2 + khalf:
// khalf 0 -> c in [0,1152), khalf 1 -> c in [1152,2312). Partials combined
// with native f64 atomicAdd (commutative -> deterministic sum; reorder error
// ~1e-13, 8 orders below spike-decision margins). Wave w owns t-octet w*8..+7
// (wave-uniform skips); spike values enter only as mask bits: acc += wf iff
// bit set -- identical f64 terms, ascending c within each half.
__global__ __launch_bounds__(256) void gemm1(const float* __restrict__ X,
                                             const double* __restrict__ Wt,
                                             double* __restrict__ Z) {
    __shared__ double Ws[16][256];   // [k][o] 32 KB
    __shared__ uint4  Xm4[4];        // 16 x u32 t-masks, one per k
    int zb = blockIdx.z;
    int b = zb >> 1, khalf = zb & 1;
    int cbeg = khalf ? KSPLIT_ : 0;
    const int NT = khalf ? 73 : 72;
    int o0 = blockIdx.y * 256;
    int t0 = blockIdx.x * 32;
    int tid = threadIdx.x;
    int lane = tid & 63, w8 = (tid >> 6) * 8;
    double acc[8][4];
#pragma unroll
    for (int tj = 0; tj < 8; ++tj)
#pragma unroll
        for (int i = 0; i < 4; ++i) acc[tj][i] = 0.0;
    const float* Xb = X + (size_t)b * C1_ * T_;

    // prefetch registers
    double2 wreg[8];
    float4 xr0, xr1;
    int kq = tid >> 2, gq = tid & 3;           // mask staging coords (tid<64)

    auto load_tile = [&](int c0) {
#pragma unroll
        for (int h = 0; h < 8; ++h) {
            int idx = h * 256 + tid;
            int i = idx >> 7, od = (idx & 127) * 2;
            int c = c0 + i;
            double2 val; val.x = 0.0; val.y = 0.0;
            if (c < C1_) val = *(const double2*)(Wt + (size_t)c * O1_ + o0 + od);
            wreg[h] = val;
        }
        if (tid < 64) {
            int c = c0 + kq, t = t0 + gq * 8;
            xr0 = make_float4(0.f, 0.f, 0.f, 0.f);
            xr1 = make_float4(0.f, 0.f, 0.f, 0.f);
            if (c < C1_) {
                if (t < T_)     xr0 = *(const float4*)(Xb + (size_t)c * T_ + t);
                if (t + 4 < T_) xr1 = *(const float4*)(Xb + (size_t)c * T_ + t + 4);
            }
        }
    };
    auto store_tile = [&]() {
#pragma unroll
        for (int h = 0; h < 8; ++h) {
            int idx = h * 256 + tid;
            int i = idx >> 7, od = (idx & 127) * 2;
            *(double2*)(&Ws[i][od]) = wreg[h];
        }
        if (tid < 64) {
            unsigned int byte = 0;
            byte |= (xr0.x != 0.f) ? 1u   : 0u;
            byte |= (xr0.y != 0.f) ? 2u   : 0u;
            byte |= (xr0.z != 0.f) ? 4u   : 0u;
            byte |= (xr0.w != 0.f) ? 8u   : 0u;
            byte |= (xr1.x != 0.f) ? 16u  : 0u;
            byte |= (xr1.y != 0.f) ? 32u  : 0u;
            byte |= (xr1.z != 0.f) ? 64u  : 0u;
            byte |= (xr1.w != 0.f) ? 128u : 0u;
            ((unsigned char*)Xm4)[kq * 4 + gq] = (unsigned char)byte;
        }
    };

    load_tile(cbeg);
    for (int tile = 0; tile < NT; ++tile) {
        store_tile();
        __syncthreads();
        if (tile + 1 < NT) load_tile(cbeg + (tile + 1) * 16);   // overlap
        unsigned int mk[16];
        {
            uint4 q0 = Xm4[0], q1 = Xm4[1], q2 = Xm4[2], q3 = Xm4[3];
            mk[0]=q0.x; mk[1]=q0.y; mk[2]=q0.z; mk[3]=q0.w;
            mk[4]=q1.x; mk[5]=q1.y; mk[6]=q1.z; mk[7]=q1.w;
            mk[8]=q2.x; mk[9]=q2.y; mk[10]=q2.z; mk[11]=q2.w;
            mk[12]=q3.x; mk[13]=q3.y; mk[14]=q3.z; mk[15]=q3.w;
        }
#pragma unroll
        for (int k = 0; k < 16; ++k) {
            unsigned int oct = (mk[k] >> w8) & 0xffu;
            if (oct) {   // wave-uniform execz skip
                double wf[4];
#pragma unroll
                for (int i = 0; i < 4; ++i) wf[i] = Ws[k][lane + 64 * i];
#pragma unroll
                for (int tj = 0; tj < 8; ++tj) {
                    if (oct & (1u << tj)) {
#pragma unroll
                        for (int i = 0; i < 4; ++i) acc[tj][i] += wf[i];
                    }
                }
            }
        }
        __syncthreads();
    }
#pragma unroll
    for (int tj = 0; tj < 8; ++tj) {
        int t = t0 + w8 + tj;
        if (t < T_) {
            double* dst = Z + ((size_t)b * T_ + t) * O1_ + o0;
#pragma unroll
            for (int i = 0; i < 4; ++i)
                atomicAdd(&dst[lane + 64 * i], acc[tj][i]);
        }
    }
}

// ---------------- GEMM layer 2 (f64, exact R5 dense version: 0 conflicts) ----------------
// A: s1 [M, 512] f32 (exact 0/1) ; Wt: [512, 512] f64 ; Z: [M, 512] f64
__global__ __launch_bounds__(256) void gemm2(const float* __restrict__ A,
                                             const double* __restrict__ Wt,
                                             double* __restrict__ Z) {
    __shared__ double Ws[16][128];   // [k][o]
    __shared__ double As[64][17];    // [m][k] padded
    int m0 = blockIdx.x * 64;
    int o0 = blockIdx.y * 128;
    int tid = threadIdx.x;
    int to = tid & 15, tm = tid >> 4;
    double acc[8][4];
#pragma unroll
    for (int i = 0; i < 8; ++i)
#pragma unroll
        for (int j = 0; j < 4; ++j) acc[i][j] = 0.0;
    for (int c0 = 0; c0 < 512; c0 += 16) {
        {   // As: thread (m = tid>>2, ch = (tid&3)*4) reads float4, scalar LDS writes
            int m = tid >> 2, ch = (tid & 3) * 4;
            float4 v = *(const float4*)(A + (size_t)(m0 + m) * 512 + c0 + ch);
            As[m][ch + 0] = (double)v.x; As[m][ch + 1] = (double)v.y;
            As[m][ch + 2] = (double)v.z; As[m][ch + 3] = (double)v.w;
        }
#pragma unroll
        for (int h = 0; h < 4; ++h) {   // Ws: linear double2, 2-way = free
            int idx = h * 512 + tid * 2;
            int i = idx >> 7, o = idx & 127;
            *(double2*)(&Ws[i][o]) = *(const double2*)(Wt + (size_t)(c0 + i) * 512 + o0 + o);
        }
        __syncthreads();
#pragma unroll
        for (int k = 0; k < 16; ++k) {
            double wf[8], xf[4];
#pragma unroll
            for (int i = 0; i < 8; ++i) wf[i] = Ws[k][to + 16 * i];
#pragma unroll
            for (int j = 0; j < 4; ++j) xf[j] = As[tm * 4 + j][k];
#pragma unroll
            for (int i = 0; i < 8; ++i)
#pragma unroll
                for (int j = 0; j < 4; ++j) acc[i][j] = fma(wf[i], xf[j], acc[i][j]);
        }
        __syncthreads();
    }
#pragma unroll
    for (int j = 0; j < 4; ++j) {
        double* dst = Z + (size_t)(m0 + tm * 4 + j) * 512 + o0;
#pragma unroll
        for (int i = 0; i < 8; ++i) dst[to + 16 * i] = acc[i][j];
    }
}

// ---------------- GEMM layer 3 (f64 acc) ----------------
__global__ __launch_bounds__(256) void gemm3(const float* __restrict__ A,
                                             const double* __restrict__ Wt,
                                             double* __restrict__ Z) {
    __shared__ double w[512 * 16];
    for (int e = threadIdx.x; e < 4096; e += 256)
        ((double2*)w)[e] = ((const double2*)Wt)[e];
    __syncthreads();
    int m = blockIdx.x * 256 + threadIdx.x;
    if (m >= M_) return;
    double acc[O3_];
#pragma unroll
    for (int o = 0; o < O3_; ++o) acc[o] = 0.0;
    const float4* Ar = (const float4*)(A + (size_t)m * 512);
    for (int cq = 0; cq < 128; ++cq) {
        float4 a = Ar[cq];
        float av[4] = {a.x, a.y, a.z, a.w};
#pragma unroll
        for (int u = 0; u < 4; ++u)
#pragma unroll
            for (int o = 0; o < O3_; ++o) acc[o] += (double)av[u] * w[(cq * 4 + u) * 16 + o];
    }
    double* dst = Z + (size_t)m * 16;
#pragma unroll
    for (int o = 0; o < O3_; ++o) dst[o] = acc[o];
}

// ---------------- LIF scan + delay, layers 1/2 (O=512, f64 state) ----------------
// 8-batched z loads: fewer exposed HBM/L3 waits at 1 wave/CU occupancy.
__global__ void scan12(const double* __restrict__ Zin,  // [B, T, 512] f64
                       const int* __restrict__ delay,   // [512]
                       float* __restrict__ Sout,        // [B, T, 512] f32 spikes
                       float* __restrict__ sumOut) {
    int blk = blockIdx.x;
    int o = (blk & 7) * 64 + threadIdx.x;
    int b = blk >> 3;
    const double* z = Zin + (size_t)b * T_ * O1_ + o;
    float* s = Sout + (size_t)b * T_ * O1_ + o;
    int d = delay[o];
    for (int t = 0; t < d; ++t) s[(size_t)t * O1_] = 0.f;
    double cur = 0.0, vol = 0.0;
    float cnt = 0.f;
    // 296 = 37*8; tail of 4 handled after.
    for (int t8 = 0; t8 < 296; t8 += 8) {
        double zb[8];
#pragma unroll
        for (int u = 0; u < 8; ++u) zb[u] = z[(size_t)(t8 + u) * O1_];
#pragma unroll
        for (int u = 0; u < 8; ++u) {
            int t = t8 + u;
            cur = cur * 0.75 + zb[u];
            vol = vol * 0.97 + cur;
            float sp = (vol >= 1.25) ? 1.f : 0.f;
            if (sp > 0.f) vol = 0.0;
            int tw = t + d;
            if (tw < T_) { s[(size_t)tw * O1_] = sp; cnt += sp; }
        }
    }
    {
        double zb[4];
#pragma unroll
        for (int u = 0; u < 4; ++u) zb[u] = z[(size_t)(296 + u) * O1_];
#pragma unroll
        for (int u = 0; u < 4; ++u) {
            int t = 296 + u;
            cur = cur * 0.75 + zb[u];
            vol = vol * 0.97 + cur;
            float sp = (vol >= 1.25) ? 1.f : 0.f;
            if (sp > 0.f) vol = 0.0;
            int tw = t + d;
            if (tw < T_) { s[(size_t)tw * O1_] = sp; cnt += sp; }
        }
    }
    for (int off = 32; off; off >>= 1) cnt += __shfl_down(cnt, off);
    if (threadIdx.x == 0) atomicAdd(sumOut, cnt);
}

// ---------------- LIF scan + delay, layer 3 (O=10, f64 state) ----------------
__global__ void scan3(const double* __restrict__ Z3,  // [M, 16] f64
                      const int* __restrict__ d3,     // [10]
                      float* __restrict__ out,        // d_out: [B, 10, 300] f32
                      float* __restrict__ sumOut) {
    __shared__ double zt[T_ * 16];
    int b = blockIdx.x;
    const double2* src = (const double2*)(Z3 + (size_t)b * T_ * 16);
    for (int e = threadIdx.x; e < T_ * 8; e += 64)
        ((double2*)zt)[e] = src[e];
    __syncthreads();
    int o = threadIdx.x;
    if (o < O3_) {
        int d = d3[o];
        float* dst = out + (size_t)b * O3_ * T_ + (size_t)o * T_;
        for (int t = 0; t < d; ++t) dst[t] = 0.f;
        double cur = 0.0, vol = 0.0;
        float cnt = 0.f;
        for (int t = 0; t < T_; ++t) {
            cur = cur * 0.75 + zt[t * 16 + o];
            vol = vol * 0.97 + cur;
            float sp = (vol >= 1.25) ? 1.f : 0.f;
            if (sp > 0.f) vol = 0.0;
            int tw = t + d;
            if (tw < T_) { dst[tw] = sp; cnt += sp; }
        }
        atomicAdd(sumOut, cnt);
    }
}

__global__ void finalize(const float* __restrict__ sums, float* __restrict__ out) {
    if (threadIdx.x == 0) {
        out[0] = (float)((double)sums[0] / (double)(B_ * O1_ * T_));
        out[1] = (float)((double)sums[1] / (double)(B_ * O2_ * T_));
        out[2] = (float)((double)sums[2] / (double)(B_ * O3_ * T_));
    }
}

extern "C" void kernel_launch(void* const* d_in, const int* in_sizes, int n_in,
                              void* d_out, int out_size, void* d_ws, size_t ws_size,
                              hipStream_t stream) {
    const float* spike = (const float*)d_in[0];
    const float* v1 = (const float*)d_in[1];
    const float* g1 = (const float*)d_in[2];
    const float* v2 = (const float*)d_in[3];
    const float* g2 = (const float*)d_in[4];
    const float* v3 = (const float*)d_in[5];
    const float* g3 = (const float*)d_in[6];
    const int* d1 = (const int*)d_in[7];
    const int* d2 = (const int*)d_in[8];
    const int* d3 = (const int*)d_in[9];
    float* out = (float*)d_out;

    // Workspace (same layout as R3-R9 pass): ~72 MB total.
    double* dw = (double*)d_ws;
    size_t off = 0;
    double* f1  = dw + off; off += 512;
    double* f2  = dw + off; off += 512;
    double* f3  = dw + off; off += 16;
    double* Wt1 = dw + off; off += (size_t)C1_ * O1_;
    double* Wt2 = dw + off; off += 512 * 512;
    double* Wt3 = dw + off; off += 512 * 16;
    double* zA  = dw + off; off += (size_t)M_ * 512;
    double* z3b = dw + off; off += (size_t)M_ * 16;
    float* fw = (float*)(dw + off);
    float* sB   = fw;                        // f32 spikes, M*512
    float* sums = fw + (size_t)M_ * 512;     // 4 floats
    (void)ws_size; (void)out_size; (void)in_sizes; (void)n_in;

    hipMemsetAsync(sums, 0, 4 * sizeof(float), stream);
    hipMemsetAsync(zA, 0, (size_t)M_ * 512 * sizeof(double), stream);  // for K-split atomics

    calc_f<<<512, 256, 0, stream>>>(v1, g1, f1, O1_, C1_);
    calc_f<<<512, 256, 0, stream>>>(v2, g2, f2, O2_, O1_);
    calc_f<<<O3_, 256, 0, stream>>>(v3, g3, f3, O3_, O2_);

    transpose_scale<<<dim3((C1_ + 31) / 32, 16), dim3(32, 8), 0, stream>>>(v1, f1, Wt1, O1_, C1_, O1_);
    transpose_scale<<<dim3(16, 16), dim3(32, 8), 0, stream>>>(v2, f2, Wt2, O2_, O1_, O2_);
    transpose_scale<<<dim3(16, 1), dim3(32, 8), 0, stream>>>(v3, f3, Wt3, O3_, O2_, 16);

    // gemm1: 10 t-chunks x 2 o-halves (256) x (32 b x 2 k-halves) = 1280 blocks (~5/CU)
    gemm1<<<dim3(10, 2, B_ * 2), 256, 0, stream>>>(spike, Wt1, zA);   // zA += z1 (f64)
    scan12<<<256, 64, 0, stream>>>(zA, d1, sB, sums + 0);             // sB = s1 (f32)
    gemm2<<<dim3(M_ / 64, 4), 256, 0, stream>>>(sB, Wt2, zA);         // zA = z2 (overwrite)
    scan12<<<256, 64, 0, stream>>>(zA, d2, sB, sums + 1);             // sB = s2
    gemm3<<<(M_ + 255) / 256, 256, 0, stream>>>(sB, Wt3, z3b);        // z3b = z3
    scan3<<<B_, 64, 0, stream>>>(z3b, d3, out, sums + 2);
    finalize<<<1, 64, 0, stream>>>(sums, out + (size_t)B_ * O3_ * T_);
}